// Round 11
// baseline (98.887 us; speedup 1.0000x reference)
//
#include <hip/hip_runtime.h>
#include <hip/hip_bf16.h>

#define B_    8
#define Q_    64
#define C_    512
#define HW_   256
#define E_    512
#define HATT_ 128
#define HMLP_ 512
#define NCLS_ 14
#define NLAB_ 64

typedef unsigned short u16;
typedef unsigned int   u32;
typedef __attribute__((ext_vector_type(8))) short short8;   // 8 bf16
typedef __attribute__((ext_vector_type(4))) float f32x4;

// ws layout (bytes) — total 12,097,536 < 12,582,912 (proven available R2):
//   pPTb @ 0       : 8x512x64 bf16 p^T [b][c][q]                  512 KB
//   pA   @ 524288  : 512x2 f32 attn-mass partials                   4 KB
//   perm @ 528384  : 512 int label-sorted bq list (bq | l<<16)      2 KB
//   Dl   @ 530432  : 64x128 f32 beta@W_att_h (atomic-accum, memset) 32 KB
//   Gf   @ 563200  : 64x512 f32 gamma (final, +b_film)            128 KB
//   Bf   @ 694272  : 64x512 f32 beta  (final, +b_film)            128 KB
//   W1bf @ 825344  : 512x512 bf16 W_mlp1                          512 KB
//   attA @ 1349632 : 512x256 bf16 attn [bq][n] (rounded)          256 KB
//   fT   @ 1611776 : 8x256x512 bf16 feature^T [b][n][c]             2 MB
//   WgT  @ 3708928 : 64 x [16ss][128h][4slot] bf16x8 gamma-scaled,  8 MB
//                    pre-swizzled (slot = g' ^ ((h>>1)&3)) so linear
//                    DMA into LDS yields the conflict-free tile.

__device__ __forceinline__ float gelu_fast(float x) {
    const float ax = fabsf(x);
    const float t  = __builtin_amdgcn_rcpf(1.0f + 0.3275911f * ax);
    const float p  = t * (0.254829592f +
                     t * (-0.284496736f +
                     t * (1.421413741f +
                     t * (-1.453152027f +
                     t * 1.061405429f))));
    const float e  = __expf(-x * x);
    const float er = copysignf(1.0f - p * e, x);
    return 0.5f * x * (1.0f + er);
}
__device__ __forceinline__ float sigmoid_(float x) {
    return 1.0f / (1.0f + __expf(-x));
}
__device__ __forceinline__ u16 f2bf(float x) {              // RNE f32->bf16
    u32 u = __float_as_uint(x);
    u32 r = (u + 0x7fffu + ((u >> 16) & 1u)) >> 16;
    return (u16)r;
}
__device__ __forceinline__ float bf2f(u16 u) {
    return __uint_as_float(((u32)u) << 16);
}
__device__ __forceinline__ u32 cvt_pk_bf16(float lo, float hi) {
    u32 r;
    asm("v_cvt_pk_bf16_f32 %0, %1, %2" : "=v"(r) : "v"(lo), "v"(hi));
    return r;
}
// async global->LDS DMA, 16B/lane; LDS dest = wave-uniform base + lane*16
__device__ __forceinline__ void gl2lds16(const void* gsrc, void* ldsdst) {
    __builtin_amdgcn_global_load_lds(
        (const __attribute__((address_space(1))) u32*)gsrc,
        (__attribute__((address_space(3))) u32*)ldsdst, 16, 0, 0);
}

// ---------------------------------------------------------------------------
// K1 prep_gbp2: 64 blocks (lgroup of 8 labels x jslice of 128) x 256 thr.
// Gf/Bf[l][c] = b_film + qt[l] @ W_film (final). W_film read 8x total (not 64x).
// ---------------------------------------------------------------------------
__global__ __launch_bounds__(256) void prep_gbp2(
    const float* __restrict__ qt, const float* __restrict__ W_film,
    const float* __restrict__ b_film,
    float* __restrict__ Gf, float* __restrict__ Bf) {
    __shared__ float q_s[8][512];                  // 16 KB
    const int bid = blockIdx.x, t = threadIdx.x;
    const int lg = bid >> 3, js = bid & 7, j0 = js * 128;

    const float4* qsrc = (const float4*)(qt + (size_t)lg * 8 * 512);
    #pragma unroll
    for (int k = 0; k < 4; ++k)
        ((float4*)q_s)[k * 256 + t] = qsrc[k * 256 + t];
    __syncthreads();

    const int tl = t >> 5, jq = t & 31;
    const int j = j0 + jq * 4;
    f32x4 a;
    { const float4 bv = *(const float4*)&b_film[j];
      a.x = bv.x; a.y = bv.y; a.z = bv.z; a.w = bv.w; }
    const float* wp = W_film + j;
    #pragma unroll 8
    for (int c = 0; c < 512; ++c) {
        const float4 w = *(const float4*)(wp + (size_t)c * 1024);
        const float q = q_s[tl][c];
        a.x += q * w.x; a.y += q * w.y; a.z += q * w.z; a.w += q * w.w;
    }
    const int l = lg * 8 + tl;
    if (j < 512) *(f32x4*)&Gf[(size_t)l * 512 + j] = a;
    else         *(f32x4*)&Bf[(size_t)l * 512 + j - 512] = a;
}

// ---------------------------------------------------------------------------
// K2 prep_rest: 577 blocks x 256 thr.
//  [0,256)   fT[b][n][c] = bf16(feature[b][c][n])
//  [256,320) W1bf = bf16(W_mlp1)
//  320       counting sort of label_ids -> perm
//  [321,577) (l,cq): WgT pre-scaled+pre-swizzled; Dl atomic partials
// ---------------------------------------------------------------------------
__global__ __launch_bounds__(256) void prep_rest(
    const float* __restrict__ feature, const float* __restrict__ W_mlp1,
    const int* __restrict__ label_ids, const float* __restrict__ W_att_h,
    const float* __restrict__ Gf, const float* __restrict__ Bf,
    u16* __restrict__ W1bf, u16* __restrict__ fT, int* __restrict__ perm,
    u16* __restrict__ WgT, float* __restrict__ Dl) {

    __shared__ __align__(16) char sm[16896];
    const int bid = blockIdx.x, t = threadIdx.x;

    if (bid < 256) {                       // ---- fT transpose
        float (*tile)[65] = (float(*)[65])sm;
        const int b = bid >> 5, c0 = ((bid >> 2) & 7) * 64, n0 = (bid & 3) * 64;
        const float* fb = feature + (size_t)b * C_ * HW_;
        const int cl = t >> 2, nq = t & 3;
        #pragma unroll
        for (int i = 0; i < 4; ++i) {
            float4 v = *(const float4*)&fb[(c0 + cl) * HW_ + n0 + nq * 16 + i * 4];
            tile[cl][nq * 16 + i * 4 + 0] = v.x;
            tile[cl][nq * 16 + i * 4 + 1] = v.y;
            tile[cl][nq * 16 + i * 4 + 2] = v.z;
            tile[cl][nq * 16 + i * 4 + 3] = v.w;
        }
        __syncthreads();
        const int nl = t >> 2, cqq = t & 3;
        u16 pk[16];
        #pragma unroll
        for (int k = 0; k < 16; ++k) pk[k] = f2bf(tile[cqq * 16 + k][nl]);
        u16* dst = fT + (size_t)(b * HW_ + n0 + nl) * C_ + c0 + cqq * 16;
        *(uint4*)dst       = *(uint4*)pk;
        *(uint4*)(dst + 8) = *(uint4*)(pk + 8);
    } else if (bid < 320) {                // ---- W1 -> bf16
        const int b2 = bid - 256;
        #pragma unroll
        for (int k = 0; k < 2; ++k) {
            const int idx = (b2 * 512 + k * 256 + t) * 8;
            float4 v0 = *(const float4*)&W_mlp1[idx];
            float4 v1 = *(const float4*)&W_mlp1[idx + 4];
            u16 pk[8] = {f2bf(v0.x), f2bf(v0.y), f2bf(v0.z), f2bf(v0.w),
                         f2bf(v1.x), f2bf(v1.y), f2bf(v1.z), f2bf(v1.w)};
            *(uint4*)&W1bf[idx] = *(uint4*)pk;
        }
    } else if (bid == 320) {               // ---- counting sort by label
        int* cnt = (int*)sm;
        if (t < 64) cnt[t] = 0;
        __syncthreads();
        const int l0 = label_ids[t], l1 = label_ids[t + 256];
        atomicAdd(&cnt[l0], 1);
        atomicAdd(&cnt[l1], 1);
        __syncthreads();
        if (t == 0) {
            int run = 0;
            for (int i = 0; i < 64; ++i) { const int c = cnt[i]; cnt[i] = run; run += c; }
        }
        __syncthreads();
        const int p0 = atomicAdd(&cnt[l0], 1);
        perm[p0] = t | (l0 << 16);
        const int p1 = atomicAdd(&cnt[l1], 1);
        perm[p1] = (t + 256) | (l1 << 16);
    } else {                               // ---- WgT + Dl partials
        float* g_s  = (float*)sm;          // 128
        float* b_s  = g_s + 128;           // 128
        float* dred = b_s + 128;           // 256
        const int wb = bid - 321;
        const int l = wb >> 2, cq = wb & 3;

        if (t < 128) {
            const int c = cq * 128 + t;
            g_s[t] = Gf[(size_t)l * 512 + c];
            b_s[t] = Bf[(size_t)l * 512 + c];
        }
        __syncthreads();

        const int h = t & 127, ch = t >> 7;
        const int hswz = (h >> 1) & 3;
        float dl = 0.f;
        #pragma unroll
        for (int sl = 0; sl < 2; ++sl) {
            const int ss = cq * 4 + ch * 2 + sl;    // superstep in [0,16)
            char* dst = (char*)WgT + (size_t)l * 131072 + ss * 8192 + h * 64;
            #pragma unroll
            for (int g = 0; g < 4; ++g) {
                u16 pk[8];
                #pragma unroll
                for (int j = 0; j < 8; ++j) {
                    const int cl = ch * 64 + sl * 32 + g * 8 + j;
                    const float w = W_att_h[(size_t)(cq * 128 + cl) * HATT_ + h];
                    pk[j] = f2bf(g_s[cl] * w);
                    dl += b_s[cl] * w;
                }
                *(uint4*)(dst + ((g ^ hswz) * 16)) = *(uint4*)pk;
            }
        }
        dred[t] = dl;
        __syncthreads();
        if (t < 128)
            atomicAdd(&Dl[(size_t)l * 128 + t], dred[t] + dred[128 + t]);
    }
}

// ---------------------------------------------------------------------------
// K3 attn_gemm: 1024 blocks x 256 thr (4 waves: 2 wm x 2 wc), (bq, nh) each.
// Counted-vmcnt 2-deep DMA pipeline (T4): per ss
//   {ds_read buf[s&1]; lgkmcnt(0)+SB; s_barrier; STAGE(s+2->buf[s&1]);
//    16 MFMA; SB; vmcnt(4); SB; s_barrier}   -- never drains vmcnt to 0.
// Epilogue: gelu -> attn (rounded bf16) -> attA + pA. No pooled pass here.
// ---------------------------------------------------------------------------
__global__ __launch_bounds__(256, 4) void attn_gemm(
    const float* __restrict__ W_att_f, const float* __restrict__ b_att_f,
    const float* __restrict__ b_att_h, const float* __restrict__ Dl,
    const int*   __restrict__ perm,    const u16* __restrict__ WgT,
    const u16*   __restrict__ fT,
    u16* __restrict__ attA, float* __restrict__ pA) {

    __shared__ __align__(16) char Ash[2][8192];    // 128n x 32c bf16, swizzled
    __shared__ __align__(16) char Bsh[2][8192];    // 128h x 32c bf16, swizzled
    __shared__ float d_s[HATT_];
    __shared__ float wf_s[HATT_];
    __shared__ float attn_part[2][128];
    __shared__ float attn_s[128];

    const int t = threadIdx.x;
    const int idx = blockIdx.x;
    const int srank2 = (idx & 7) * 128 + (idx >> 3);   // XCD-chunked
    const int r = srank2 >> 1, nh = srank2 & 1;
    const int pe = perm[r];
    const int bq = pe & 0xffff, l = pe >> 16;
    const int b = bq >> 6;

    // prologue loads fully drain before any DMA is issued
    if (t < HATT_) {
        d_s[t]  = b_att_h[t] + Dl[(size_t)l * 128 + t];
        wf_s[t] = W_att_f[t];
    }

    const u16* fTb = fT + (size_t)b * HW_ * C_ + (size_t)nh * 128 * C_;
    const u16* Wl  = WgT + (size_t)l * 65536;      // elements

    const int an0  = t >> 2;                       // n row; it adds 64
    const int asl0 = (t & 3) ^ ((an0 >> 1) & 3);   // inverse swizzle on source

    #define STAGE(s_) {                                                       \
        _Pragma("unroll")                                                     \
        for (int it = 0; it < 2; ++it)                                        \
            gl2lds16(fTb + (size_t)(it * 64 + an0) * C_ + (s_) * 32           \
                         + asl0 * 8,                                          \
                     &Ash[(s_) & 1][(it * 256 + t) * 16]);                    \
        _Pragma("unroll")                                                     \
        for (int it = 0; it < 2; ++it)                                        \
            gl2lds16(Wl + (size_t)(s_) * 4096 + (size_t)(it * 256 + t) * 8,   \
                     &Bsh[(s_) & 1][(it * 256 + t) * 16]);                    \
    }

    const int lane = t & 63, w = t >> 6;
    const int wm = w >> 1, wc = w & 1;             // 2 n-halves x 2 h-halves
    const int lr = lane & 15, lk = lane >> 4;

    const f32x4 zero = {0.f, 0.f, 0.f, 0.f};
    f32x4 acc[4][4];
    #pragma unroll
    for (int mi = 0; mi < 4; ++mi)
        #pragma unroll
        for (int ni = 0; ni < 4; ++ni) acc[mi][ni] = zero;

    STAGE(0);
    STAGE(1);
    asm volatile("s_waitcnt vmcnt(4)" ::: "memory");   // tile 0 landed
    __builtin_amdgcn_sched_barrier(0);
    __builtin_amdgcn_s_barrier();

    #pragma unroll
    for (int s = 0; s < 16; ++s) {
        const char* Ab = Ash[s & 1];
        const char* Bb = Bsh[s & 1];
        short8 af[4], bf[4];
        #pragma unroll
        for (int mi = 0; mi < 4; ++mi) {
            const int nl = wm * 64 + mi * 16 + lr;
            af[mi] = *(const short8*)(Ab + nl * 64 + ((lk ^ ((nl >> 1) & 3)) * 16));
        }
        #pragma unroll
        for (int ni = 0; ni < 4; ++ni) {
            const int h = wc * 64 + ni * 16 + lr;
            bf[ni] = *(const short8*)(Bb + h * 64 + ((lk ^ ((h >> 1) & 3)) * 16));
        }
        asm volatile("s_waitcnt lgkmcnt(0)" ::: "memory");
        __builtin_amdgcn_sched_barrier(0);
        __builtin_amdgcn_s_barrier();              // all waves done reading buf
        if (s < 14) STAGE(s + 2);                  // overwrite just-read buf
        #pragma unroll
        for (int mi = 0; mi < 4; ++mi)
            #pragma unroll
            for (int ni = 0; ni < 4; ++ni)
                acc[mi][ni] = __builtin_amdgcn_mfma_f32_16x16x32_bf16(
                    af[mi], bf[ni], acc[mi][ni], 0, 0, 0);
        if (s < 15) {
            __builtin_amdgcn_sched_barrier(0);     // keep MFMAs above the wait
            if (s < 14) asm volatile("s_waitcnt vmcnt(4)" ::: "memory");
            else        asm volatile("s_waitcnt vmcnt(0)" ::: "memory");
            __builtin_amdgcn_sched_barrier(0);
            __builtin_amdgcn_s_barrier();          // tile s+1 visible to all
        }
    }

    // ---- epilogue: gelu(hidden + D) . wf   (C/D: col(h)=lr, row(n)=lk*4+j)
    #pragma unroll
    for (int mi = 0; mi < 4; ++mi) {
        #pragma unroll
        for (int j = 0; j < 4; ++j) {
            float sum = 0.f;
            #pragma unroll
            for (int ni = 0; ni < 4; ++ni) {
                const int h = wc * 64 + ni * 16 + lr;
                sum += gelu_fast(acc[mi][ni][j] + d_s[h]) * wf_s[h];
            }
            sum += __shfl_xor(sum, 1);
            sum += __shfl_xor(sum, 2);
            sum += __shfl_xor(sum, 4);
            sum += __shfl_xor(sum, 8);
            if (lr == 0) attn_part[wc][wm * 64 + mi * 16 + lk * 4 + j] = sum;
        }
    }
    __syncthreads();
    if (t < 128) {
        const u16 ab = f2bf(sigmoid_(attn_part[0][t] + attn_part[1][t] + b_att_f[0]));
        attA[(size_t)bq * 256 + nh * 128 + t] = ab;    // rounded attn to ws
        attn_s[t] = bf2f(ab);                          // consistent for pA
    }
    __syncthreads();
    if (t < 64) {
        float a = attn_s[t] + attn_s[t + 64];
        #pragma unroll
        for (int m = 1; m < 64; m <<= 1) a += __shfl_xor(a, m);
        if (t == 0) pA[bq * 2 + nh] = a;
    }
}

// ---------------------------------------------------------------------------
// K4 pool_gemm: 64 blocks (b x 8 c-slices of 64) x 256 thr (4 waves x 16c).
// p^T[b][c][q] = sum_n feature[b][c][n] * attn[bq][n]  via MFMA,
// A = feature f32 cvt'd on the fly, B = attA bf16. Output bf16.
// ---------------------------------------------------------------------------
__global__ __launch_bounds__(256) void pool_gemm(
    const float* __restrict__ feature, const u16* __restrict__ attA,
    u16* __restrict__ pPTb) {

    const int t = threadIdx.x, bid = blockIdx.x;
    const int b = bid >> 3, c0 = (bid & 7) * 64;
    const int w = t >> 6, lane = t & 63;
    const int lr = lane & 15, lk = lane >> 4;
    const int crow = c0 + w * 16 + lr;

    const float* fr = feature + ((size_t)b * C_ + crow) * HW_;
    const u16*   ar = attA + (size_t)b * 64 * 256;

    const f32x4 zero = {0.f, 0.f, 0.f, 0.f};
    f32x4 acc[4];
    #pragma unroll
    for (int ni = 0; ni < 4; ++ni) acc[ni] = zero;

    #pragma unroll
    for (int ss = 0; ss < 8; ++ss) {
        const int n0 = ss * 32 + lk * 8;
        const float4 a0 = *(const float4*)&fr[n0];
        const float4 a1 = *(const float4*)&fr[n0 + 4];
        union { uint4 u; short8 s; } au;
        au.u.x = cvt_pk_bf16(a0.x, a0.y);
        au.u.y = cvt_pk_bf16(a0.z, a0.w);
        au.u.z = cvt_pk_bf16(a1.x, a1.y);
        au.u.w = cvt_pk_bf16(a1.z, a1.w);
        #pragma unroll
        for (int ni = 0; ni < 4; ++ni) {
            const short8 bf = *(const short8*)(ar + (size_t)(ni * 16 + lr) * 256 + n0);
            acc[ni] = __builtin_amdgcn_mfma_f32_16x16x32_bf16(au.s, bf, acc[ni], 0, 0, 0);
        }
    }
    // D: col(q) = lr, row(c) = lk*4 + j
    #pragma unroll
    for (int ni = 0; ni < 4; ++ni)
        #pragma unroll
        for (int j = 0; j < 4; ++j) {
            const int c = c0 + w * 16 + lk * 4 + j;
            pPTb[((size_t)b * C_ + c) * 64 + ni * 16 + lr] = f2bf(acc[ni][j]);
        }
}

// ---------------------------------------------------------------------------
// K5 mlp_head: 256 blocks x 512 thr, 2 bq per block.
// pooled = (Gf*p + Bf*A)/(A+eps); z = gelu(pooled@W1+b1); out = z@W2 + b2.
// ---------------------------------------------------------------------------
__global__ __launch_bounds__(512) void mlp_head(
    const int*   __restrict__ label_ids,
    const float* __restrict__ Gf, const float* __restrict__ Bf,
    const float* __restrict__ b_mlp1, const float* __restrict__ W_mlp2,
    const float* __restrict__ b_mlp2, const u16* __restrict__ pPTb,
    const float* __restrict__ pA,     const u16* __restrict__ W1bf,
    float* __restrict__ out) {

    __shared__ float pooled_s[2][C_];
    __shared__ float zred[2][2][HMLP_];
    __shared__ float z_s[2][HMLP_];
    __shared__ float red_s[32 * NCLS_];

    const int t = threadIdx.x;
    const int bq0 = blockIdx.x * 2;

    {
        const int bqi = t >> 8, cc = (t & 255) * 2;
        const int bq = bq0 + bqi, l = label_ids[bq];
        const int b = bq >> 6, q = bq & 63;
        const float A = pA[bq * 2] + pA[bq * 2 + 1];
        const float inv = 1.0f / (A + 1e-8f);
        #pragma unroll
        for (int i = 0; i < 2; ++i) {
            const int c = cc + i;
            const float p = bf2f(pPTb[((size_t)b * C_ + c) * 64 + q]);
            pooled_s[bqi][c] = (Gf[(size_t)l * 512 + c] * p
                              + Bf[(size_t)l * 512 + c] * A) * inv;
        }
    }
    __syncthreads();

    {
        const int hp = t & 255, cg = t >> 8;
        float z00 = 0.f, z01 = 0.f, z10 = 0.f, z11 = 0.f;
        const u16* wp = W1bf + hp * 2;
        #pragma unroll 8
        for (int c = cg * 256; c < cg * 256 + 256; ++c) {
            const u32 v = *(const u32*)(wp + (size_t)c * HMLP_);
            const float w0 = __uint_as_float(v << 16);
            const float w1 = __uint_as_float(v & 0xffff0000u);
            const float pa = pooled_s[0][c], pb = pooled_s[1][c];
            z00 += pa * w0; z01 += pa * w1;
            z10 += pb * w0; z11 += pb * w1;
        }
        float2 a0 = {z00, z01}, a1 = {z10, z11};
        *(float2*)&zred[cg][0][hp * 2] = a0;
        *(float2*)&zred[cg][1][hp * 2] = a1;
    }
    __syncthreads();
    {
        const int bqi = t >> 8, h2 = (t & 255) * 2;
        #pragma unroll
        for (int i = 0; i < 2; ++i) {
            const int h = h2 + i;
            z_s[bqi][h] = gelu_fast(zred[0][bqi][h] + zred[1][bqi][h] + b_mlp1[h]);
        }
    }
    __syncthreads();

    #pragma unroll
    for (int bqi = 0; bqi < 2; ++bqi) {
        if (t < 448) {
            const int o = t % 14, seg = t / 14;
            float s = 0.f;
            #pragma unroll
            for (int k = 0; k < 16; ++k) {
                const int h = seg * 16 + k;
                s += z_s[bqi][h] * W_mlp2[h * NCLS_ + o];
            }
            red_s[seg * NCLS_ + o] = s;
        }
        __syncthreads();
        if (t < NCLS_) {
            float s = b_mlp2[t];
            #pragma unroll
            for (int seg = 0; seg < 32; ++seg) s += red_s[seg * NCLS_ + t];
            out[(bq0 + bqi) * NCLS_ + t] = s;
        }
        __syncthreads();
    }
}

// ---------------------------------------------------------------------------
extern "C" void kernel_launch(void* const* d_in, const int* in_sizes, int n_in,
                              void* d_out, int out_size, void* d_ws, size_t ws_size,
                              hipStream_t stream) {
    const float* feature   = (const float*)d_in[0];
    const int*   label_ids = (const int*)  d_in[1];
    const float* qt        = (const float*)d_in[2];
    const float* W_film    = (const float*)d_in[3];
    const float* b_film    = (const float*)d_in[4];
    const float* W_att_h   = (const float*)d_in[5];
    const float* b_att_h   = (const float*)d_in[6];
    const float* W_att_f   = (const float*)d_in[7];
    const float* b_att_f   = (const float*)d_in[8];
    const float* W_mlp1    = (const float*)d_in[9];
    const float* b_mlp1    = (const float*)d_in[10];
    const float* W_mlp2    = (const float*)d_in[11];
    const float* b_mlp2    = (const float*)d_in[12];
    float* out = (float*)d_out;

    char* wsb   = (char*)d_ws;
    u16*   pPTb = (u16*)  wsb;                   // 512 KB
    float* pA   = (float*)(wsb + 524288);        // 4 KB
    int*   perm = (int*)  (wsb + 528384);        // 2 KB
    float* Dl   = (float*)(wsb + 530432);        // 32 KB (memset below)
    float* Gf   = (float*)(wsb + 563200);        // 128 KB
    float* Bf   = (float*)(wsb + 694272);        // 128 KB
    u16*   W1bf = (u16*)  (wsb + 825344);        // 512 KB
    u16*   attA = (u16*)  (wsb + 1349632);       // 256 KB
    u16*   fTp  = (u16*)  (wsb + 1611776);       // 2 MB
    u16*   WgT  = (u16*)  (wsb + 3708928);       // 8 MB

    hipMemsetAsync(Dl, 0, 32768, stream);
    hipLaunchKernelGGL(prep_gbp2, dim3(64), dim3(256), 0, stream,
                       qt, W_film, b_film, Gf, Bf);
    hipLaunchKernelGGL(prep_rest, dim3(577), dim3(256), 0, stream,
                       feature, W_mlp1, label_ids, W_att_h, Gf, Bf,
                       W1bf, fTp, perm, WgT, Dl);
    hipLaunchKernelGGL(attn_gemm, dim3(1024), dim3(256), 0, stream,
                       W_att_f, b_att_f, b_att_h, Dl, perm, WgT, fTp,
                       attA, pA);
    hipLaunchKernelGGL(pool_gemm, dim3(64), dim3(256), 0, stream,
                       feature, attA, pPTb);
    hipLaunchKernelGGL(mlp_head, dim3(256), dim3(512), 0, stream,
                       label_ids, Gf, Bf, b_mlp1, W_mlp2, b_mlp2,
                       pPTb, pA, W1bf, out);
}

// Round 12
// 93.472 us; speedup vs baseline: 1.0579x; 1.0579x over previous
//
#include <hip/hip_runtime.h>
#include <hip/hip_bf16.h>

#define B_    8
#define Q_    64
#define C_    512
#define HW_   256
#define E_    512
#define HATT_ 128
#define HMLP_ 512
#define NCLS_ 14
#define NLAB_ 64

typedef unsigned short u16;
typedef unsigned int   u32;
typedef __attribute__((ext_vector_type(8))) short short8;   // 8 bf16
typedef __attribute__((ext_vector_type(4))) float f32x4;

// ws layout (bytes) — total 12,195,840 < 12,582,912 (proven available R2):
//   pPTb @ 0       : 8x512x64 bf16 p^T [b][c][q]                  512 KB
//   pA   @ 524288  : 512x2 f32 attn-mass partials                   4 KB
//   perm @ 528384  : 512 int label-sorted bq list (bq | l<<16)      2 KB
//   Dlp  @ 530432  : 256x128 f32 (l,cq)-partials of beta@W_att_h  128 KB
//   Gf   @ 661504  : 64x512 f32 gamma (final, +b_film)            128 KB
//   Bf   @ 792576  : 64x512 f32 beta  (final, +b_film)            128 KB
//   W1bf @ 923648  : 512x512 bf16 W_mlp1                          512 KB
//   attA @ 1447936 : 512x256 bf16 attn [bq][n] (rounded)          256 KB
//   fT   @ 1710080 : 8x256x512 bf16 feature^T [b][n][c]             2 MB
//   WgT  @ 3807232 : 64 x [16ss][128h][4slot] bf16x8 gamma-scaled,  8 MB
//                    pre-swizzled (slot = g' ^ ((h>>1)&3)) so linear
//                    DMA into LDS yields the conflict-free tile.

__device__ __forceinline__ float gelu_fast(float x) {
    const float ax = fabsf(x);
    const float t  = __builtin_amdgcn_rcpf(1.0f + 0.3275911f * ax);
    const float p  = t * (0.254829592f +
                     t * (-0.284496736f +
                     t * (1.421413741f +
                     t * (-1.453152027f +
                     t * 1.061405429f))));
    const float e  = __expf(-x * x);
    const float er = copysignf(1.0f - p * e, x);
    return 0.5f * x * (1.0f + er);
}
__device__ __forceinline__ float sigmoid_(float x) {
    return 1.0f / (1.0f + __expf(-x));
}
__device__ __forceinline__ u16 f2bf(float x) {              // RNE f32->bf16
    u32 u = __float_as_uint(x);
    u32 r = (u + 0x7fffu + ((u >> 16) & 1u)) >> 16;
    return (u16)r;
}
__device__ __forceinline__ float bf2f(u16 u) {
    return __uint_as_float(((u32)u) << 16);
}
__device__ __forceinline__ u32 cvt_pk_bf16(float lo, float hi) {
    u32 r;
    asm("v_cvt_pk_bf16_f32 %0, %1, %2" : "=v"(r) : "v"(lo), "v"(hi));
    return r;
}
// async global->LDS DMA, 16B/lane; LDS dest = wave-uniform base + lane*16
__device__ __forceinline__ void gl2lds16(const void* gsrc, void* ldsdst) {
    __builtin_amdgcn_global_load_lds(
        (const __attribute__((address_space(1))) u32*)gsrc,
        (__attribute__((address_space(3))) u32*)ldsdst, 16, 0, 0);
}

// ---------------------------------------------------------------------------
// K1 prep_gbp2: 64 blocks (lgroup of 8 labels x jslice of 128) x 256 thr.
// Gf/Bf[l][c] = b_film + qt[l] @ W_film (final). W_film read 8x total.
// ---------------------------------------------------------------------------
__global__ __launch_bounds__(256) void prep_gbp2(
    const float* __restrict__ qt, const float* __restrict__ W_film,
    const float* __restrict__ b_film,
    float* __restrict__ Gf, float* __restrict__ Bf) {
    __shared__ float q_s[8][512];                  // 16 KB
    const int bid = blockIdx.x, t = threadIdx.x;
    const int lg = bid >> 3, js = bid & 7, j0 = js * 128;

    const float4* qsrc = (const float4*)(qt + (size_t)lg * 8 * 512);
    #pragma unroll
    for (int k = 0; k < 4; ++k)
        ((float4*)q_s)[k * 256 + t] = qsrc[k * 256 + t];
    __syncthreads();

    const int tl = t >> 5, jq = t & 31;
    const int j = j0 + jq * 4;
    f32x4 a;
    { const float4 bv = *(const float4*)&b_film[j];
      a.x = bv.x; a.y = bv.y; a.z = bv.z; a.w = bv.w; }
    const float* wp = W_film + j;
    #pragma unroll 8
    for (int c = 0; c < 512; ++c) {
        const float4 w = *(const float4*)(wp + (size_t)c * 1024);
        const float q = q_s[tl][c];
        a.x += q * w.x; a.y += q * w.y; a.z += q * w.z; a.w += q * w.w;
    }
    const int l = lg * 8 + tl;
    if (j < 512) *(f32x4*)&Gf[(size_t)l * 512 + j] = a;
    else         *(f32x4*)&Bf[(size_t)l * 512 + j - 512] = a;
}

// ---------------------------------------------------------------------------
// K2 prep_rest: 577 blocks x 256 thr.
//  [0,256)   fT[b][n][c] = bf16(feature[b][c][n])
//  [256,320) W1bf = bf16(W_mlp1)
//  320       counting sort of label_ids -> perm
//  [321,577) (l,cq): WgT pre-scaled+pre-swizzled; Dlp partials (non-atomic)
// ---------------------------------------------------------------------------
__global__ __launch_bounds__(256) void prep_rest(
    const float* __restrict__ feature, const float* __restrict__ W_mlp1,
    const int* __restrict__ label_ids, const float* __restrict__ W_att_h,
    const float* __restrict__ Gf, const float* __restrict__ Bf,
    u16* __restrict__ W1bf, u16* __restrict__ fT, int* __restrict__ perm,
    u16* __restrict__ WgT, float* __restrict__ Dlp) {

    __shared__ __align__(16) char sm[16896];
    const int bid = blockIdx.x, t = threadIdx.x;

    if (bid < 256) {                       // ---- fT transpose
        float (*tile)[65] = (float(*)[65])sm;
        const int b = bid >> 5, c0 = ((bid >> 2) & 7) * 64, n0 = (bid & 3) * 64;
        const float* fb = feature + (size_t)b * C_ * HW_;
        const int cl = t >> 2, nq = t & 3;
        #pragma unroll
        for (int i = 0; i < 4; ++i) {
            float4 v = *(const float4*)&fb[(c0 + cl) * HW_ + n0 + nq * 16 + i * 4];
            tile[cl][nq * 16 + i * 4 + 0] = v.x;
            tile[cl][nq * 16 + i * 4 + 1] = v.y;
            tile[cl][nq * 16 + i * 4 + 2] = v.z;
            tile[cl][nq * 16 + i * 4 + 3] = v.w;
        }
        __syncthreads();
        const int nl = t >> 2, cqq = t & 3;
        u16 pk[16];
        #pragma unroll
        for (int k = 0; k < 16; ++k) pk[k] = f2bf(tile[cqq * 16 + k][nl]);
        u16* dst = fT + (size_t)(b * HW_ + n0 + nl) * C_ + c0 + cqq * 16;
        *(uint4*)dst       = *(uint4*)pk;
        *(uint4*)(dst + 8) = *(uint4*)(pk + 8);
    } else if (bid < 320) {                // ---- W1 -> bf16
        const int b2 = bid - 256;
        #pragma unroll
        for (int k = 0; k < 2; ++k) {
            const int idx = (b2 * 512 + k * 256 + t) * 8;
            float4 v0 = *(const float4*)&W_mlp1[idx];
            float4 v1 = *(const float4*)&W_mlp1[idx + 4];
            u16 pk[8] = {f2bf(v0.x), f2bf(v0.y), f2bf(v0.z), f2bf(v0.w),
                         f2bf(v1.x), f2bf(v1.y), f2bf(v1.z), f2bf(v1.w)};
            *(uint4*)&W1bf[idx] = *(uint4*)pk;
        }
    } else if (bid == 320) {               // ---- counting sort by label
        int* cnt = (int*)sm;
        if (t < 64) cnt[t] = 0;
        __syncthreads();
        const int l0 = label_ids[t], l1 = label_ids[t + 256];
        atomicAdd(&cnt[l0], 1);
        atomicAdd(&cnt[l1], 1);
        __syncthreads();
        if (t == 0) {
            int run = 0;
            for (int i = 0; i < 64; ++i) { const int c = cnt[i]; cnt[i] = run; run += c; }
        }
        __syncthreads();
        const int p0 = atomicAdd(&cnt[l0], 1);
        perm[p0] = t | (l0 << 16);
        const int p1 = atomicAdd(&cnt[l1], 1);
        perm[p1] = (t + 256) | (l1 << 16);
    } else {                               // ---- WgT + Dlp partials
        float* g_s  = (float*)sm;          // 128
        float* b_s  = g_s + 128;           // 128
        float* dred = b_s + 128;           // 256
        const int wb = bid - 321;
        const int l = wb >> 2, cq = wb & 3;

        if (t < 128) {
            const int c = cq * 128 + t;
            g_s[t] = Gf[(size_t)l * 512 + c];
            b_s[t] = Bf[(size_t)l * 512 + c];
        }
        __syncthreads();

        const int h = t & 127, ch = t >> 7;
        const int hswz = (h >> 1) & 3;
        float dl = 0.f;
        #pragma unroll
        for (int sl = 0; sl < 2; ++sl) {
            const int ss = cq * 4 + ch * 2 + sl;    // superstep in [0,16)
            char* dst = (char*)WgT + (size_t)l * 131072 + ss * 8192 + h * 64;
            #pragma unroll
            for (int g = 0; g < 4; ++g) {
                u16 pk[8];
                #pragma unroll
                for (int j = 0; j < 8; ++j) {
                    const int cl = ch * 64 + sl * 32 + g * 8 + j;
                    const float w = W_att_h[(size_t)(cq * 128 + cl) * HATT_ + h];
                    pk[j] = f2bf(g_s[cl] * w);
                    dl += b_s[cl] * w;
                }
                *(uint4*)(dst + ((g ^ hswz) * 16)) = *(uint4*)pk;
            }
        }
        dred[t] = dl;
        __syncthreads();
        if (t < 128)
            Dlp[(size_t)(l * 4 + cq) * 128 + t] = dred[t] + dred[128 + t];
    }
}

// ---------------------------------------------------------------------------
// K3 attn_gemm: 1024 blocks x 256 thr (4 waves: 2 wm x 2 wc), (bq, nh) each.
// Counted-vmcnt 2-deep DMA pipeline (T4): per ss
//   {ds_read buf[s&1]; lgkmcnt(0)+SB; s_barrier; STAGE(s+2->buf[s&1]);
//    16 MFMA; SB; vmcnt(4); SB; s_barrier}   -- never drains vmcnt to 0.
// Epilogue: gelu -> attn (rounded bf16) -> attA + pA. No pooled pass here.
// ---------------------------------------------------------------------------
__global__ __launch_bounds__(256, 4) void attn_gemm(
    const float* __restrict__ W_att_f, const float* __restrict__ b_att_f,
    const float* __restrict__ b_att_h, const float* __restrict__ Dlp,
    const int*   __restrict__ perm,    const u16* __restrict__ WgT,
    const u16*   __restrict__ fT,
    u16* __restrict__ attA, float* __restrict__ pA) {

    __shared__ __align__(16) char Ash[2][8192];    // 128n x 32c bf16, swizzled
    __shared__ __align__(16) char Bsh[2][8192];    // 128h x 32c bf16, swizzled
    __shared__ float d_s[HATT_];
    __shared__ float wf_s[HATT_];
    __shared__ float attn_part[2][128];
    __shared__ float attn_s[128];

    const int t = threadIdx.x;
    const int idx = blockIdx.x;
    const int srank2 = (idx & 7) * 128 + (idx >> 3);   // XCD-chunked
    const int r = srank2 >> 1, nh = srank2 & 1;
    const int pe = perm[r];
    const int bq = pe & 0xffff, l = pe >> 16;
    const int b = bq >> 6;

    if (t < HATT_) {
        d_s[t] = b_att_h[t]
               + Dlp[(size_t)(l * 4 + 0) * 128 + t]
               + Dlp[(size_t)(l * 4 + 1) * 128 + t]
               + Dlp[(size_t)(l * 4 + 2) * 128 + t]
               + Dlp[(size_t)(l * 4 + 3) * 128 + t];
        wf_s[t] = W_att_f[t];
    }

    const u16* fTb = fT + (size_t)b * HW_ * C_ + (size_t)nh * 128 * C_;
    const u16* Wl  = WgT + (size_t)l * 65536;      // elements

    const int an0  = t >> 2;                       // n row; it adds 64
    const int asl0 = (t & 3) ^ ((an0 >> 1) & 3);   // inverse swizzle on source

    #define STAGE(s_) {                                                       \
        _Pragma("unroll")                                                     \
        for (int it = 0; it < 2; ++it)                                        \
            gl2lds16(fTb + (size_t)(it * 64 + an0) * C_ + (s_) * 32           \
                         + asl0 * 8,                                          \
                     &Ash[(s_) & 1][(it * 256 + t) * 16]);                    \
        _Pragma("unroll")                                                     \
        for (int it = 0; it < 2; ++it)                                        \
            gl2lds16(Wl + (size_t)(s_) * 4096 + (size_t)(it * 256 + t) * 8,   \
                     &Bsh[(s_) & 1][(it * 256 + t) * 16]);                    \
    }

    const int lane = t & 63, w = t >> 6;
    const int wm = w >> 1, wc = w & 1;             // 2 n-halves x 2 h-halves
    const int lr = lane & 15, lk = lane >> 4;

    const f32x4 zero = {0.f, 0.f, 0.f, 0.f};
    f32x4 acc[4][4];
    #pragma unroll
    for (int mi = 0; mi < 4; ++mi)
        #pragma unroll
        for (int ni = 0; ni < 4; ++ni) acc[mi][ni] = zero;

    STAGE(0);
    STAGE(1);
    asm volatile("s_waitcnt vmcnt(4)" ::: "memory");   // tile 0 landed
    __builtin_amdgcn_sched_barrier(0);
    __builtin_amdgcn_s_barrier();

    #pragma unroll
    for (int s = 0; s < 16; ++s) {
        const char* Ab = Ash[s & 1];
        const char* Bb = Bsh[s & 1];
        short8 af[4], bf[4];
        #pragma unroll
        for (int mi = 0; mi < 4; ++mi) {
            const int nl = wm * 64 + mi * 16 + lr;
            af[mi] = *(const short8*)(Ab + nl * 64 + ((lk ^ ((nl >> 1) & 3)) * 16));
        }
        #pragma unroll
        for (int ni = 0; ni < 4; ++ni) {
            const int h = wc * 64 + ni * 16 + lr;
            bf[ni] = *(const short8*)(Bb + h * 64 + ((lk ^ ((h >> 1) & 3)) * 16));
        }
        asm volatile("s_waitcnt lgkmcnt(0)" ::: "memory");
        __builtin_amdgcn_sched_barrier(0);
        __builtin_amdgcn_s_barrier();              // all waves done reading buf
        if (s < 14) STAGE(s + 2);                  // overwrite just-read buf
        #pragma unroll
        for (int mi = 0; mi < 4; ++mi)
            #pragma unroll
            for (int ni = 0; ni < 4; ++ni)
                acc[mi][ni] = __builtin_amdgcn_mfma_f32_16x16x32_bf16(
                    af[mi], bf[ni], acc[mi][ni], 0, 0, 0);
        if (s < 15) {
            __builtin_amdgcn_sched_barrier(0);     // keep MFMAs above the wait
            if (s < 14) asm volatile("s_waitcnt vmcnt(4)" ::: "memory");
            else        asm volatile("s_waitcnt vmcnt(0)" ::: "memory");
            __builtin_amdgcn_sched_barrier(0);
            __builtin_amdgcn_s_barrier();          // tile s+1 visible to all
        }
    }

    // ---- epilogue: gelu(hidden + D) . wf   (C/D: col(h)=lr, row(n)=lk*4+j)
    #pragma unroll
    for (int mi = 0; mi < 4; ++mi) {
        #pragma unroll
        for (int j = 0; j < 4; ++j) {
            float sum = 0.f;
            #pragma unroll
            for (int ni = 0; ni < 4; ++ni) {
                const int h = wc * 64 + ni * 16 + lr;
                sum += gelu_fast(acc[mi][ni][j] + d_s[h]) * wf_s[h];
            }
            sum += __shfl_xor(sum, 1);
            sum += __shfl_xor(sum, 2);
            sum += __shfl_xor(sum, 4);
            sum += __shfl_xor(sum, 8);
            if (lr == 0) attn_part[wc][wm * 64 + mi * 16 + lk * 4 + j] = sum;
        }
    }
    __syncthreads();
    if (t < 128) {
        const u16 ab = f2bf(sigmoid_(attn_part[0][t] + attn_part[1][t] + b_att_f[0]));
        attA[(size_t)bq * 256 + nh * 128 + t] = ab;    // rounded attn to ws
        attn_s[t] = bf2f(ab);                          // consistent for pA
    }
    __syncthreads();
    if (t < 64) {
        float a = attn_s[t] + attn_s[t + 64];
        #pragma unroll
        for (int m = 1; m < 64; m <<= 1) a += __shfl_xor(a, m);
        if (t == 0) pA[bq * 2 + nh] = a;
    }
}

// ---------------------------------------------------------------------------
// K4 pool_gemm: 64 blocks (b x 8 c-slices of 64) x 256 thr (4 waves x 16c).
// p^T[b][c][q] = sum_n feature[b][c][n] * attn[bq][n]  via MFMA,
// A = feature f32 cvt'd on the fly, B = attA bf16. Output bf16.
// ---------------------------------------------------------------------------
__global__ __launch_bounds__(256) void pool_gemm(
    const float* __restrict__ feature, const u16* __restrict__ attA,
    u16* __restrict__ pPTb) {

    const int t = threadIdx.x, bid = blockIdx.x;
    const int b = bid >> 3, c0 = (bid & 7) * 64;
    const int w = t >> 6, lane = t & 63;
    const int lr = lane & 15, lk = lane >> 4;
    const int crow = c0 + w * 16 + lr;

    const float* fr = feature + ((size_t)b * C_ + crow) * HW_;
    const u16*   ar = attA + (size_t)b * 64 * 256;

    const f32x4 zero = {0.f, 0.f, 0.f, 0.f};
    f32x4 acc[4];
    #pragma unroll
    for (int ni = 0; ni < 4; ++ni) acc[ni] = zero;

    #pragma unroll
    for (int ss = 0; ss < 8; ++ss) {
        const int n0 = ss * 32 + lk * 8;
        const float4 a0 = *(const float4*)&fr[n0];
        const float4 a1 = *(const float4*)&fr[n0 + 4];
        union { uint4 u; short8 s; } au;
        au.u.x = cvt_pk_bf16(a0.x, a0.y);
        au.u.y = cvt_pk_bf16(a0.z, a0.w);
        au.u.z = cvt_pk_bf16(a1.x, a1.y);
        au.u.w = cvt_pk_bf16(a1.z, a1.w);
        #pragma unroll
        for (int ni = 0; ni < 4; ++ni) {
            const short8 bf = *(const short8*)(ar + (size_t)(ni * 16 + lr) * 256 + n0);
            acc[ni] = __builtin_amdgcn_mfma_f32_16x16x32_bf16(au.s, bf, acc[ni], 0, 0, 0);
        }
    }
    // D: col(q) = lr, row(c) = lk*4 + j
    #pragma unroll
    for (int ni = 0; ni < 4; ++ni)
        #pragma unroll
        for (int j = 0; j < 4; ++j) {
            const int c = c0 + w * 16 + lk * 4 + j;
            pPTb[((size_t)b * C_ + c) * 64 + ni * 16 + lr] = f2bf(acc[ni][j]);
        }
}

// ---------------------------------------------------------------------------
// K5 mlp_head: 256 blocks x 512 thr, 2 bq per block.
// pooled = (Gf*p + Bf*A)/(A+eps); z = gelu(pooled@W1+b1); out = z@W2 + b2.
// ---------------------------------------------------------------------------
__global__ __launch_bounds__(512) void mlp_head(
    const int*   __restrict__ label_ids,
    const float* __restrict__ Gf, const float* __restrict__ Bf,
    const float* __restrict__ b_mlp1, const float* __restrict__ W_mlp2,
    const float* __restrict__ b_mlp2, const u16* __restrict__ pPTb,
    const float* __restrict__ pA,     const u16* __restrict__ W1bf,
    float* __restrict__ out) {

    __shared__ float pooled_s[2][C_];
    __shared__ float zred[2][2][HMLP_];
    __shared__ float z_s[2][HMLP_];
    __shared__ float red_s[32 * NCLS_];

    const int t = threadIdx.x;
    const int bq0 = blockIdx.x * 2;

    {
        const int bqi = t >> 8, cc = (t & 255) * 2;
        const int bq = bq0 + bqi, l = label_ids[bq];
        const int b = bq >> 6, q = bq & 63;
        const float A = pA[bq * 2] + pA[bq * 2 + 1];
        const float inv = 1.0f / (A + 1e-8f);
        #pragma unroll
        for (int i = 0; i < 2; ++i) {
            const int c = cc + i;
            const float p = bf2f(pPTb[((size_t)b * C_ + c) * 64 + q]);
            pooled_s[bqi][c] = (Gf[(size_t)l * 512 + c] * p
                              + Bf[(size_t)l * 512 + c] * A) * inv;
        }
    }
    __syncthreads();

    {
        const int hp = t & 255, cg = t >> 8;
        float z00 = 0.f, z01 = 0.f, z10 = 0.f, z11 = 0.f;
        const u16* wp = W1bf + hp * 2;
        #pragma unroll 8
        for (int c = cg * 256; c < cg * 256 + 256; ++c) {
            const u32 v = *(const u32*)(wp + (size_t)c * HMLP_);
            const float w0 = __uint_as_float(v << 16);
            const float w1 = __uint_as_float(v & 0xffff0000u);
            const float pa = pooled_s[0][c], pb = pooled_s[1][c];
            z00 += pa * w0; z01 += pa * w1;
            z10 += pb * w0; z11 += pb * w1;
        }
        float2 a0 = {z00, z01}, a1 = {z10, z11};
        *(float2*)&zred[cg][0][hp * 2] = a0;
        *(float2*)&zred[cg][1][hp * 2] = a1;
    }
    __syncthreads();
    {
        const int bqi = t >> 8, h2 = (t & 255) * 2;
        #pragma unroll
        for (int i = 0; i < 2; ++i) {
            const int h = h2 + i;
            z_s[bqi][h] = gelu_fast(zred[0][bqi][h] + zred[1][bqi][h] + b_mlp1[h]);
        }
    }
    __syncthreads();

    #pragma unroll
    for (int bqi = 0; bqi < 2; ++bqi) {
        if (t < 448) {
            const int o = t % 14, seg = t / 14;
            float s = 0.f;
            #pragma unroll
            for (int k = 0; k < 16; ++k) {
                const int h = seg * 16 + k;
                s += z_s[bqi][h] * W_mlp2[h * NCLS_ + o];
            }
            red_s[seg * NCLS_ + o] = s;
        }
        __syncthreads();
        if (t < NCLS_) {
            float s = b_mlp2[t];
            #pragma unroll
            for (int seg = 0; seg < 32; ++seg) s += red_s[seg * NCLS_ + t];
            out[(bq0 + bqi) * NCLS_ + t] = s;
        }
        __syncthreads();
    }
}

// ---------------------------------------------------------------------------
extern "C" void kernel_launch(void* const* d_in, const int* in_sizes, int n_in,
                              void* d_out, int out_size, void* d_ws, size_t ws_size,
                              hipStream_t stream) {
    const float* feature   = (const float*)d_in[0];
    const int*   label_ids = (const int*)  d_in[1];
    const float* qt        = (const float*)d_in[2];
    const float* W_film    = (const float*)d_in[3];
    const float* b_film    = (const float*)d_in[4];
    const float* W_att_h   = (const float*)d_in[5];
    const float* b_att_h   = (const float*)d_in[6];
    const float* W_att_f   = (const float*)d_in[7];
    const float* b_att_f   = (const float*)d_in[8];
    const float* W_mlp1    = (const float*)d_in[9];
    const float* b_mlp1    = (const float*)d_in[10];
    const float* W_mlp2    = (const float*)d_in[11];
    const float* b_mlp2    = (const float*)d_in[12];
    float* out = (float*)d_out;

    char* wsb   = (char*)d_ws;
    u16*   pPTb = (u16*)  wsb;                   // 512 KB
    float* pA   = (float*)(wsb + 524288);        // 4 KB
    int*   perm = (int*)  (wsb + 528384);        // 2 KB
    float* Dlp  = (float*)(wsb + 530432);        // 128 KB
    float* Gf   = (float*)(wsb + 661504);        // 128 KB
    float* Bf   = (float*)(wsb + 792576);        // 128 KB
    u16*   W1bf = (u16*)  (wsb + 923648);        // 512 KB
    u16*   attA = (u16*)  (wsb + 1447936);       // 256 KB
    u16*   fTp  = (u16*)  (wsb + 1710080);       // 2 MB
    u16*   WgT  = (u16*)  (wsb + 3807232);       // 8 MB

    hipLaunchKernelGGL(prep_gbp2, dim3(64), dim3(256), 0, stream,
                       qt, W_film, b_film, Gf, Bf);
    hipLaunchKernelGGL(prep_rest, dim3(577), dim3(256), 0, stream,
                       feature, W_mlp1, label_ids, W_att_h, Gf, Bf,
                       W1bf, fTp, perm, WgT, Dlp);
    hipLaunchKernelGGL(attn_gemm, dim3(1024), dim3(256), 0, stream,
                       W_att_f, b_att_f, b_att_h, Dlp, perm, WgT, fTp,
                       attA, pA);
    hipLaunchKernelGGL(pool_gemm, dim3(64), dim3(256), 0, stream,
                       feature, attA, pPTb);
    hipLaunchKernelGGL(mlp_head, dim3(256), dim3(512), 0, stream,
                       label_ids, Gf, Bf, b_mlp1, W_mlp2, b_mlp2,
                       pPTb, pA, W1bf, out);
}